// Round 8
// baseline (730.623 us; speedup 1.0000x reference)
//
#include <hip/hip_runtime.h>
#include <hip/hip_cooperative_groups.h>

namespace cg = cooperative_groups;

#define LVLS  16
#define TSZ   524288u          // 2^19
#define TMASK (TSZ - 1u)
#define PRIME 2654435761u

// floor(16 * g^l), g = 128^(1/15) — matches np float64 floor then f32 cast
__constant__ float RES[LVLS] = {16.f, 22.f, 30.f, 42.f, 58.f, 80.f, 111.f, 153.f,
                                212.f, 294.f, 406.f, 561.f, 776.f, 1072.f, 1482.f, 2048.f};

typedef __bf16 bf16x8 __attribute__((ext_vector_type(8)));
typedef float  f32x4  __attribute__((ext_vector_type(4)));

union Frag {
    uint4          q;
    unsigned       u[4];
    unsigned short s[8];
    bf16x8         v;
};

static __device__ __forceinline__ unsigned short f2bf(float f) {
    unsigned u = __float_as_uint(f);
    u += 0x7FFFu + ((u >> 16) & 1u);          // RNE; inputs finite, non-NaN
    return (unsigned short)(u >> 16);
}
static __device__ __forceinline__ unsigned pack2(float a, float b) {
    unsigned ua = __float_as_uint(a), ub = __float_as_uint(b);
    ua += 0x7FFFu + ((ua >> 16) & 1u);
    ub += 0x7FFFu + ((ub >> 16) & 1u);
    return (ua >> 16) | (ub & 0xFFFF0000u);
}
static __device__ __forceinline__ void lds_fence() {
    asm volatile("s_waitcnt lgkmcnt(0)" ::: "memory");
}
static __device__ __forceinline__ unsigned cell_key(float px, float py) {
    unsigned cx = (unsigned)(px * 256.f); cx = cx > 255u ? 255u : cx;
    unsigned cy = (unsigned)(py * 256.f); cy = cy > 255u ? 255u : cy;
    return (cy << 8) | cx;
}

// ================= device phase helpers (shared by mega + fallback) =================

static __device__ void dev_zero_hist(unsigned* __restrict__ hist, int gt, int G) {
    uint4 z; z.x = z.y = z.z = z.w = 0u;
    for (int i = gt; i < 16384; i += G) ((uint4*)hist)[i] = z;
}

// B layout: lane holds col n=lane&15, k=quad*8+j. Hidden-unit storage slot
// eta = 4c+t (ReLU writes pack into b64); W1/W2 rows remapped: orig=(eta&3)*16+(eta>>2).
static __device__ void dev_frag_build(const float* __restrict__ W0,
                                      const float* __restrict__ W1,
                                      const float* __restrict__ W2,
                                      uint4* __restrict__ frg, int tid) {
    const int lane = tid & 63;
    const int wv   = tid >> 6;
    const int c = lane & 15, quad = lane >> 4;
    for (int set = wv; set < 14; set += 4) {
        Frag t;
        if (set < 4) {
            const int f = set;
            #pragma unroll
            for (int j = 0; j < 8; ++j)
                t.s[j] = f2bf(W0[(quad * 8 + j) * 64 + f * 16 + c]);
        } else if (set < 12) {
            const int ff = set - 4;
            const int kt = ff >> 2, tt = ff & 3;
            #pragma unroll
            for (int j = 0; j < 8; ++j) {
                const int eta = kt * 32 + quad * 8 + j;
                const int orig = (eta & 3) * 16 + (eta >> 2);
                t.s[j] = f2bf(W1[orig * 64 + tt * 16 + c]);
            }
        } else {
            const int f = set - 12;
            #pragma unroll
            for (int j = 0; j < 8; ++j) {
                const int eta = f * 32 + quad * 8 + j;
                const int orig = (eta & 3) * 16 + (eta >> 2);
                const float v = (c < 3) ? W2[orig * 3 + c] : 0.f;
                t.s[j] = f2bf(v);
            }
        }
        frg[set * 64 + lane] = t.q;
    }
}

static __device__ void dev_hist(const float2* __restrict__ x,
                                unsigned* __restrict__ hist, int N, int gt, int G) {
    const int nq = (N + 3) >> 2;
    for (int q = gt; q < nq; q += G) {
        const int i0 = q * 4;
        if (i0 + 3 < N) {
            const float4 a = ((const float4*)x)[q * 2 + 0];
            const float4 b = ((const float4*)x)[q * 2 + 1];
            atomicAdd(&hist[cell_key(a.x, a.y)], 1u);
            atomicAdd(&hist[cell_key(a.z, a.w)], 1u);
            atomicAdd(&hist[cell_key(b.x, b.y)], 1u);
            atomicAdd(&hist[cell_key(b.z, b.w)], 1u);
        } else {
            for (int i = i0; i < N; ++i) {
                const float2 v = x[i];
                atomicAdd(&hist[cell_key(v.x, v.y)], 1u);
            }
        }
    }
}

static __device__ void dev_scanA(unsigned* __restrict__ hist,
                                 unsigned* __restrict__ totals,
                                 int chunk, int tid, unsigned* ps) {
    const int cb = chunk * 256;
    uint4 m = ((const uint4*)hist)[cb + tid];
    const unsigned s = m.x + m.y + m.z + m.w;
    ps[tid] = s;
    __syncthreads();
    for (int off = 1; off < 256; off <<= 1) {
        const unsigned v = (tid >= off) ? ps[tid - off] : 0u;
        __syncthreads();
        ps[tid] += v;
        __syncthreads();
    }
    const unsigned excl = ps[tid] - s;
    uint4 o;
    o.x = excl;
    o.y = excl + m.x;
    o.z = o.y + m.y;
    o.w = o.z + m.z;
    ((uint4*)hist)[cb + tid] = o;
    if (tid == 255) totals[chunk] = ps[255];
}

static __device__ void dev_scanB(const unsigned* __restrict__ totals,
                                 unsigned* __restrict__ base, int t) {
    const unsigned mine = totals[t];
    unsigned v = mine;
    #pragma unroll
    for (int off = 1; off < 64; off <<= 1) {
        const unsigned u = __shfl_up(v, off);
        if (t >= off) v += u;
    }
    base[t] = v - mine;
}

static __device__ void dev_scatter(const float2* __restrict__ x,
                                   unsigned* __restrict__ hist,
                                   const unsigned* __restrict__ base,
                                   int* __restrict__ perm, float2* __restrict__ xs,
                                   int N, int gt, int G) {
    for (int n = gt; n < N; n += G) {
        const float2 v = x[n];
        const unsigned key = cell_key(v.x, v.y);
        const unsigned pos = base[key >> 10] + atomicAdd(&hist[key], 1u);
        perm[pos] = n;
        xs[pos] = v;
    }
}

// fused encode+MLP for tiles [gw*tpw, ...): lane quad*16+c owns point n0+c,
// levels quad*4..+3; packs its A0 fragment directly in registers.
static __device__ void dev_fused_range(
    const float2* __restrict__ xs, const float* __restrict__ tables,
    const uint4* __restrict__ frg, const float* __restrict__ b0,
    const float* __restrict__ b1, const float* __restrict__ b2,
    const int* __restrict__ perm, float* __restrict__ out, int N,
    int gw, int totalWaves, int lane, unsigned short (*hs)[72])
{
    const int c    = lane & 15;
    const int quad = lane >> 4;

    Frag B0f[4], B1f[8], B2f[2];
    #pragma unroll
    for (int t = 0; t < 4; ++t) B0f[t].q = frg[t * 64 + lane];
    #pragma unroll
    for (int f = 0; f < 8; ++f) B1f[f].q = frg[(4 + f) * 64 + lane];
    #pragma unroll
    for (int f = 0; f < 2; ++f) B2f[f].q = frg[(12 + f) * 64 + lane];

    float bias0[4], bias1[4];
    #pragma unroll
    for (int t = 0; t < 4; ++t) { bias0[t] = b0[t * 16 + c]; bias1[t] = b1[t * 16 + c]; }
    const float bias2 = (c < 3) ? b2[c] : 0.f;

    const int nTiles = (N + 15) >> 4;
    const int tpw = (nTiles + totalWaves - 1) / totalWaves;
    const int t0 = gw * tpw;
    int t1 = t0 + tpw; if (t1 > nTiles) t1 = nTiles;

    #pragma unroll 1
    for (int tile = t0; tile < t1; ++tile) {
        const int n0 = tile * 16;
        const int p  = min(n0 + c, N - 1);
        const float2 xy = xs[p];

        Frag a0;
        #pragma unroll
        for (int pr = 0; pr < 2; ++pr) {
            unsigned idx[8];
            float uxa[2], uya[2];
            #pragma unroll
            for (int j = 0; j < 2; ++j) {
                const int l = quad * 4 + 2 * pr + j;
                const float r = RES[l];
                const float sx = xy.x * r, sy = xy.y * r;
                const float fx = floorf(sx), fy = floorf(sy);
                uxa[j] = sx - fx; uya[j] = sy - fy;
                const unsigned ix = (unsigned)(int)fx, iy = (unsigned)(int)fy;
                const unsigned hy0 = iy * PRIME, hy1 = (iy + 1u) * PRIME;
                idx[4 * j + 0] = (ix ^ hy0) & TMASK;
                idx[4 * j + 1] = ((ix + 1u) ^ hy0) & TMASK;
                idx[4 * j + 2] = (ix ^ hy1) & TMASK;
                idx[4 * j + 3] = ((ix + 1u) ^ hy1) & TMASK;
            }
            float2 f[8];
            #pragma unroll
            for (int j = 0; j < 2; ++j) {
                const int l = quad * 4 + 2 * pr + j;
                const float2* tb = (const float2*)(tables + (size_t)l * (TSZ * 2));
                f[4 * j + 0] = tb[idx[4 * j + 0]];
                f[4 * j + 1] = tb[idx[4 * j + 1]];
                f[4 * j + 2] = tb[idx[4 * j + 2]];
                f[4 * j + 3] = tb[idx[4 * j + 3]];
            }
            #pragma unroll
            for (int j = 0; j < 2; ++j) {
                const float w00 = (1.f - uxa[j]) * (1.f - uya[j]);
                const float w10 = uxa[j] * (1.f - uya[j]);
                const float w01 = (1.f - uxa[j]) * uya[j];
                const float w11 = uxa[j] * uya[j];
                const float e0 = w00 * f[4*j+0].x + w10 * f[4*j+1].x + w01 * f[4*j+2].x + w11 * f[4*j+3].x;
                const float e1 = w00 * f[4*j+0].y + w10 * f[4*j+1].y + w01 * f[4*j+2].y + w11 * f[4*j+3].y;
                a0.u[2 * pr + j] = pack2(e0, e1);
            }
        }

        // ---- layer 0: 32 -> 64 ----
        f32x4 acc[4];
        #pragma unroll
        for (int t = 0; t < 4; ++t) {
            f32x4 cin = {bias0[t], bias0[t], bias0[t], bias0[t]};
            acc[t] = __builtin_amdgcn_mfma_f32_16x16x32_bf16(a0.v, B0f[t].v, cin, 0, 0, 0);
        }

        lds_fence();
        #pragma unroll
        for (int rr = 0; rr < 4; ++rr) {
            uint2 pk;
            pk.x = pack2(fmaxf(acc[0][rr], 0.f), fmaxf(acc[1][rr], 0.f));
            pk.y = pack2(fmaxf(acc[2][rr], 0.f), fmaxf(acc[3][rr], 0.f));
            *(uint2*)&hs[quad * 4 + rr][4 * c] = pk;
        }
        lds_fence();
        Frag a1[2];
        #pragma unroll
        for (int kt = 0; kt < 2; ++kt)
            a1[kt].q = *(const uint4*)&hs[c][kt * 32 + quad * 8];

        // ---- layer 1: 64 -> 64 ----
        #pragma unroll
        for (int t = 0; t < 4; ++t) {
            f32x4 cin = {bias1[t], bias1[t], bias1[t], bias1[t]};
            cin = __builtin_amdgcn_mfma_f32_16x16x32_bf16(a1[0].v, B1f[t].v, cin, 0, 0, 0);
            acc[t] = __builtin_amdgcn_mfma_f32_16x16x32_bf16(a1[1].v, B1f[4 + t].v, cin, 0, 0, 0);
        }

        lds_fence();
        #pragma unroll
        for (int rr = 0; rr < 4; ++rr) {
            uint2 pk;
            pk.x = pack2(fmaxf(acc[0][rr], 0.f), fmaxf(acc[1][rr], 0.f));
            pk.y = pack2(fmaxf(acc[2][rr], 0.f), fmaxf(acc[3][rr], 0.f));
            *(uint2*)&hs[quad * 4 + rr][4 * c] = pk;
        }
        lds_fence();
        Frag a2[2];
        #pragma unroll
        for (int kt = 0; kt < 2; ++kt)
            a2[kt].q = *(const uint4*)&hs[c][kt * 32 + quad * 8];

        // ---- layer 2: 64 -> 3 + sigmoid + permuted store ----
        f32x4 cin2 = {bias2, bias2, bias2, bias2};
        cin2 = __builtin_amdgcn_mfma_f32_16x16x32_bf16(a2[0].v, B2f[0].v, cin2, 0, 0, 0);
        const f32x4 o = __builtin_amdgcn_mfma_f32_16x16x32_bf16(a2[1].v, B2f[1].v, cin2, 0, 0, 0);
        if (c < 3) {
            #pragma unroll
            for (int rr = 0; rr < 4; ++rr) {
                const int idx = n0 + quad * 4 + rr;
                if (idx < N) {
                    const int pi = perm ? perm[idx] : idx;
                    const float sg = 1.f / (1.f + __expf(-o[rr]));
                    out[(size_t)pi * 3 + c] = sg;
                }
            }
        }
    }
}

// ================= single cooperative mega-kernel =================
__global__ __launch_bounds__(256, 4) void ngp_mega(
    const float2* __restrict__ x, const float* __restrict__ tables,
    const float* __restrict__ W0, const float* __restrict__ b0,
    const float* __restrict__ W1, const float* __restrict__ b1,
    const float* __restrict__ W2, const float* __restrict__ b2,
    float* __restrict__ out, int N,
    uint4* __restrict__ frg, float2* __restrict__ xs, int* __restrict__ perm,
    unsigned* __restrict__ hist, unsigned* __restrict__ tot, unsigned* __restrict__ base)
{
    __shared__ __align__(16) unsigned short hscr[4][16][72];
    __shared__ unsigned ps[256];
    cg::grid_group grid = cg::this_grid();

    const int tid = threadIdx.x;
    const int gt  = blockIdx.x * 256 + tid;
    const int G   = gridDim.x * 256;

    dev_zero_hist(hist, gt, G);
    if (blockIdx.x == 0) dev_frag_build(W0, W1, W2, frg, tid);
    grid.sync();

    dev_hist(x, hist, N, gt, G);
    grid.sync();

    if (blockIdx.x < 64) dev_scanA(hist, tot, blockIdx.x, tid, ps);
    grid.sync();

    if (blockIdx.x == 0 && tid < 64) dev_scanB(tot, base, tid);
    grid.sync();

    dev_scatter(x, hist, base, perm, xs, N, gt, G);
    grid.sync();

    const int w = tid >> 6, lane = tid & 63;
    dev_fused_range(xs, tables, frg, b0, b1, b2, perm, out, N,
                    blockIdx.x * 4 + w, gridDim.x * 4, lane, hscr[w]);
}

// ================= fallback kernels (same device code, separate dispatches) =================
__global__ __launch_bounds__(256) void k_frag(const float* W0, const float* W1,
                                              const float* W2, uint4* frg) {
    dev_frag_build(W0, W1, W2, frg, threadIdx.x);
}
__global__ __launch_bounds__(256) void k_hist(const float2* x, unsigned* hist, int N) {
    dev_hist(x, hist, N, blockIdx.x * 256 + threadIdx.x, gridDim.x * 256);
}
__global__ __launch_bounds__(256) void k_scanA(unsigned* hist, unsigned* tot) {
    __shared__ unsigned ps[256];
    dev_scanA(hist, tot, blockIdx.x, threadIdx.x, ps);
}
__global__ __launch_bounds__(64) void k_scanB(const unsigned* tot, unsigned* base) {
    dev_scanB(tot, base, threadIdx.x);
}
__global__ __launch_bounds__(256) void k_scatter(const float2* x, unsigned* hist,
                                                 const unsigned* base, int* perm,
                                                 float2* xs, int N) {
    dev_scatter(x, hist, base, perm, xs, N, blockIdx.x * 256 + threadIdx.x, gridDim.x * 256);
}
__global__ __launch_bounds__(256, 4) void k_fused(const float2* xs, const float* tables,
                                                  const uint4* frg, const float* b0,
                                                  const float* b1, const float* b2,
                                                  const int* perm, float* out, int N) {
    __shared__ __align__(16) unsigned short hscr[4][16][72];
    const int w = threadIdx.x >> 6, lane = threadIdx.x & 63;
    dev_fused_range(xs, tables, frg, b0, b1, b2, perm, out, N,
                    blockIdx.x * 4 + w, gridDim.x * 4, lane, hscr[w]);
}

extern "C" void kernel_launch(void* const* d_in, const int* in_sizes, int n_in,
                              void* d_out, int out_size, void* d_ws, size_t ws_size,
                              hipStream_t stream) {
    const float2* x     = (const float2*)d_in[0];
    const float* tables = (const float*)d_in[1];
    const float* W0     = (const float*)d_in[2];
    const float* b0     = (const float*)d_in[3];
    const float* W1     = (const float*)d_in[4];
    const float* b1     = (const float*)d_in[5];
    const float* W2     = (const float*)d_in[6];
    const float* b2     = (const float*)d_in[7];
    float* out = (float*)d_out;

    int N = in_sizes[0] / 2;
    char* ws = (char*)d_ws;

    const size_t off_frag = 0;                          // 14*64*16 B
    const size_t off_xs   = 16384;
    const size_t off_perm = off_xs + (size_t)N * 8;
    const size_t off_hist = off_perm + (size_t)N * 4;
    const size_t off_tot  = off_hist + 65536 * 4;
    const size_t off_base = off_tot + 256;
    const size_t need     = off_base + 256;
    const bool use_sort = (ws_size >= need);

    uint4*    frg  = (uint4*)(ws + off_frag);
    float2*   xs   = (float2*)(ws + off_xs);
    int*      perm = (int*)(ws + off_perm);
    unsigned* hist = (unsigned*)(ws + off_hist);
    unsigned* tot  = (unsigned*)(ws + off_tot);
    unsigned* base = (unsigned*)(ws + off_base);

    bool done = false;
    if (use_sort) {
        int nb = 0;
        if (hipOccupancyMaxActiveBlocksPerMultiprocessor(&nb, (const void*)ngp_mega, 256, 0)
                != hipSuccess || nb < 1) nb = 2;
        if (nb > 4) nb = 4;
        int grid = nb * 256;               // 256 CUs
        if (grid > 1024) grid = 1024;

        void* args[] = {(void*)&x, (void*)&tables, (void*)&W0, (void*)&b0,
                        (void*)&W1, (void*)&b1, (void*)&W2, (void*)&b2,
                        (void*)&out, (void*)&N, (void*)&frg, (void*)&xs,
                        (void*)&perm, (void*)&hist, (void*)&tot, (void*)&base};
        hipError_t e = hipLaunchCooperativeKernel((const void*)ngp_mega,
                                                  dim3(grid), dim3(256), args, 0, stream);
        if (e == hipSuccess) done = true;
        else (void)hipGetLastError();      // clear error, fall through
    }

    if (!done) {
        k_frag<<<1, 256, 0, stream>>>(W0, W1, W2, frg);
        if (use_sort) {
            hipMemsetAsync(hist, 0, 65536 * 4, stream);
            k_hist<<<256, 256, 0, stream>>>(x, hist, N);
            k_scanA<<<64, 256, 0, stream>>>(hist, tot);
            k_scanB<<<1, 64, 0, stream>>>(tot, base);
            k_scatter<<<256, 256, 0, stream>>>(x, hist, base, perm, xs, N);
            k_fused<<<1024, 256, 0, stream>>>(xs, tables, frg, b0, b1, b2, perm, out, N);
        } else {
            k_fused<<<1024, 256, 0, stream>>>(x, tables, frg, b0, b1, b2, nullptr, out, N);
        }
    }
}